// Round 1
// baseline (538.333 us; speedup 1.0000x reference)
//
#include <hip/hip_runtime.h>
#include <hip/hip_bf16.h>
#include <math.h>

#define BATCH 2
#define NQ    13125
#define DM    256
#define NH    8
#define HDIM  32
#define NL    3
#define NP    4
#define NTOK  13125   // total value tokens per batch (10000+2500+625)

// ---------------- generic fp32 tiled GEMM: C = A(MxK) * B(KxN) + bias ----------------
#define TM 64
#define TN 64
#define TK 16

__device__ __forceinline__ void gemm_tile(const float* __restrict__ A,
                                          const float* __restrict__ Bm,
                                          const float* __restrict__ bias,
                                          float* __restrict__ C,
                                          int M, int N, int K, int m0, int n0)
{
    __shared__ float As[TK][TM];   // [k][m]
    __shared__ float Bs[TK][TN];   // [k][n]
    const int tid = threadIdx.x;
    const int tx = tid & 15;       // -> n
    const int ty = tid >> 4;       // -> m
    float acc[4][4] = {};

    const int arow = tid >> 2;           // 0..63
    const int akk  = (tid & 3) * 4;      // 0,4,8,12
    const int brow = tid >> 4;           // 0..15
    const int bnn  = (tid & 15) * 4;     // 0..60
    const bool aval = (m0 + arow) < M;
    const int  gn   = n0 + bnn;
    const bool bval = gn < N;            // N is always a multiple of 4 here

    for (int k0 = 0; k0 < K; k0 += TK) {
        float4 av = make_float4(0.f, 0.f, 0.f, 0.f);
        if (aval) av = *(const float4*)(A + (size_t)(m0 + arow) * K + k0 + akk);
        As[akk + 0][arow] = av.x;
        As[akk + 1][arow] = av.y;
        As[akk + 2][arow] = av.z;
        As[akk + 3][arow] = av.w;

        float4 bv = make_float4(0.f, 0.f, 0.f, 0.f);
        if (bval) bv = *(const float4*)(Bm + (size_t)(k0 + brow) * N + gn);
        Bs[brow][bnn + 0] = bv.x;
        Bs[brow][bnn + 1] = bv.y;
        Bs[brow][bnn + 2] = bv.z;
        Bs[brow][bnn + 3] = bv.w;

        __syncthreads();
#pragma unroll
        for (int k = 0; k < TK; ++k) {
            float4 a  = *(const float4*)&As[k][ty * 4];
            float4 bb = *(const float4*)&Bs[k][tx * 4];
            float ar[4] = {a.x, a.y, a.z, a.w};
            float br[4] = {bb.x, bb.y, bb.z, bb.w};
#pragma unroll
            for (int i = 0; i < 4; ++i)
#pragma unroll
                for (int j = 0; j < 4; ++j)
                    acc[i][j] += ar[i] * br[j];
        }
        __syncthreads();
    }

#pragma unroll
    for (int i = 0; i < 4; ++i) {
        const int m = m0 + ty * 4 + i;
        if (m >= M) continue;
#pragma unroll
        for (int j = 0; j < 4; ++j) {
            const int n = n0 + tx * 4 + j;
            if (n < N) C[(size_t)m * N + n] = acc[i][j] + bias[n];
        }
    }
}

__global__ __launch_bounds__(256) void qgemm_kernel(const float* __restrict__ A,
                                                    const float* __restrict__ W,
                                                    const float* __restrict__ bias,
                                                    float* __restrict__ C,
                                                    int M, int N, int K)
{
    const int m0 = blockIdx.y * TM;
    const int n0 = blockIdx.x * TN;
    if (m0 >= M) return;   // uniform per-block, safe before barriers
    gemm_tile(A, W, bias, C, M, N, K, m0, n0);
}

// value projection over all (batch, level) slices in one launch via grid.z
__global__ __launch_bounds__(256) void vproj_kernel(const float* __restrict__ v0,
                                                    const float* __restrict__ v1,
                                                    const float* __restrict__ v2,
                                                    const float* __restrict__ W,
                                                    const float* __restrict__ bias,
                                                    float* __restrict__ vws)
{
    const int z = blockIdx.z;          // 0..5  = b*3 + lvl
    const int b = z / 3, l = z % 3;
    const int Ms[3]   = {10000, 2500, 625};
    const int Offs[3] = {0, 10000, 12500};
    const float* Asel = (l == 0) ? v0 : ((l == 1) ? v1 : v2);
    const int M = Ms[l];
    const float* A = Asel + (size_t)b * M * DM;
    float* C = vws + ((size_t)b * NTOK + Offs[l]) * DM;
    const int m0 = blockIdx.y * TM;
    const int n0 = blockIdx.x * TN;
    if (m0 >= M) return;
    gemm_tile(A, W, bias, C, M, DM, DM, m0, n0);
}

// ---------------- sampling: one block per (b, q); 256 threads = (head, channel) ----------------
__global__ __launch_bounds__(256) void sample_kernel(const float* __restrict__ vws,
                                                     const float* __restrict__ offs,
                                                     const float* __restrict__ logits,
                                                     const float* __restrict__ refp,
                                                     float* __restrict__ mid)
{
    const int q   = blockIdx.x;          // 0..B*NQ-1
    const int b   = q / NQ;
    const int tid = threadIdx.x;
    const int h   = tid >> 5;            // head
    const int hd  = tid & 31;            // channel within head

    __shared__ float s_off[NH * NL * NP * 2];   // 192
    __shared__ float s_lg[NH * NL * NP];        // 96
    __shared__ float s_ref[NL * 2];             // 6

    if (tid < 192) s_off[tid] = offs[(size_t)q * 192 + tid];
    if (tid < 96)  s_lg[tid]  = logits[(size_t)q * 96 + tid];
    if (tid < 6)   s_ref[tid] = refp[(size_t)q * 6 + tid];
    __syncthreads();

    // softmax over L*P = 12 per head (computed redundantly in each lane of the head group)
    float w[12];
    float mx = -1e30f;
#pragma unroll
    for (int i = 0; i < 12; ++i) { w[i] = s_lg[h * 12 + i]; mx = fmaxf(mx, w[i]); }
    float ssum = 0.f;
#pragma unroll
    for (int i = 0; i < 12; ++i) { w[i] = expf(w[i] - mx); ssum += w[i]; }
    const float inv = 1.f / ssum;

    const int Hs[3] = {100, 50, 25};
    const int Wz[3] = {100, 50, 25};
    const int Lo[3] = {0, 10000, 12500};

    float acc = 0.f;
#pragma unroll
    for (int l = 0; l < NL; ++l) {
        const int Wl = Wz[l], Hl = Hs[l];
        const float fW = (float)Wl, fH = (float)Hl;
        const float rx = s_ref[l * 2 + 0];
        const float ry = s_ref[l * 2 + 1];
        const float* vb = vws + ((size_t)b * NTOK + Lo[l]) * DM + h * HDIM + hd;
#pragma unroll
        for (int p = 0; p < NP; ++p) {
            const int oi = (((h * NL) + l) * NP + p) * 2;
            // loc = ref + off/norm ; x = loc.x*W - 0.5 (align_corners=False)
            const float x = (rx + s_off[oi]     / fW) * fW - 0.5f;
            const float y = (ry + s_off[oi + 1] / fH) * fH - 0.5f;
            const float x0f = floorf(x), y0f = floorf(y);
            const int   x0 = (int)x0f,  y0 = (int)y0f;
            const float wx1 = x - x0f, wy1 = y - y0f;
            const float wx0 = 1.f - wx1, wy0 = 1.f - wy1;

            const bool xin0 = (x0 >= 0) && (x0 < Wl);
            const bool xin1 = (x0 + 1 >= 0) && (x0 + 1 < Wl);
            const bool yin0 = (y0 >= 0) && (y0 < Hl);
            const bool yin1 = (y0 + 1 >= 0) && (y0 + 1 < Hl);

            float sv = 0.f;
            if (xin0 && yin0) sv += wx0 * wy0 * vb[(size_t)(y0 * Wl + x0) * DM];
            if (xin1 && yin0) sv += wx1 * wy0 * vb[(size_t)(y0 * Wl + x0 + 1) * DM];
            if (xin0 && yin1) sv += wx0 * wy1 * vb[(size_t)((y0 + 1) * Wl + x0) * DM];
            if (xin1 && yin1) sv += wx1 * wy1 * vb[(size_t)((y0 + 1) * Wl + x0 + 1) * DM];

            acc += w[l * NP + p] * sv;
        }
    }
    mid[(size_t)q * DM + h * HDIM + hd] = acc * inv;
}

// ---------------------------------------------------------------------------------------------
extern "C" void kernel_launch(void* const* d_in, const int* in_sizes, int n_in,
                              void* d_out, int out_size, void* d_ws, size_t ws_size,
                              hipStream_t stream)
{
    const float* query  = (const float*)d_in[0];
    const float* refp   = (const float*)d_in[1];
    const float* v0     = (const float*)d_in[2];
    const float* v1     = (const float*)d_in[3];
    const float* v2     = (const float*)d_in[4];
    const float* W_val  = (const float*)d_in[5];
    const float* b_val  = (const float*)d_in[6];
    const float* W_off  = (const float*)d_in[7];
    const float* b_off  = (const float*)d_in[8];
    const float* W_attn = (const float*)d_in[9];
    const float* b_attn = (const float*)d_in[10];
    const float* W_out  = (const float*)d_in[11];
    const float* b_out  = (const float*)d_in[12];
    float* out = (float*)d_out;

    float* ws   = (float*)d_ws;
    float* vws  = ws;                                   // 2*13125*256
    float* offs = vws  + (size_t)BATCH * NTOK * DM;     // 2*13125*192
    float* lgts = offs + (size_t)BATCH * NQ * 192;      // 2*13125*96
    float* mid  = lgts + (size_t)BATCH * NQ * 96;       // 2*13125*256

    const int Mq = BATCH * NQ;   // 26250

    // 1. value projection (all 6 batch/level slices)
    {
        dim3 grid(DM / TN, (10000 + TM - 1) / TM, 6);
        vproj_kernel<<<grid, 256, 0, stream>>>(v0, v1, v2, W_val, b_val, vws);
    }
    // 2. sampling offsets: query @ W_off + b_off
    {
        dim3 grid(192 / TN, (Mq + TM - 1) / TM);
        qgemm_kernel<<<grid, 256, 0, stream>>>(query, W_off, b_off, offs, Mq, 192, DM);
    }
    // 3. attention logits: query @ W_attn + b_attn
    {
        dim3 grid((96 + TN - 1) / TN, (Mq + TM - 1) / TM);
        qgemm_kernel<<<grid, 256, 0, stream>>>(query, W_attn, b_attn, lgts, Mq, 96, DM);
    }
    // 4. softmax + bilinear sampling + head-weighted accumulation
    sample_kernel<<<Mq, 256, 0, stream>>>(vws, offs, lgts, refp, mid);
    // 5. output projection
    {
        dim3 grid(DM / TN, (Mq + TM - 1) / TM);
        qgemm_kernel<<<grid, 256, 0, stream>>>(mid, W_out, b_out, out, Mq, DM, DM);
    }
}

// Round 2
// 425.099 us; speedup vs baseline: 1.2664x; 1.2664x over previous
//
#include <hip/hip_runtime.h>
#include <hip/hip_bf16.h>
#include <math.h>

#define BATCH 2
#define NQ    13125
#define DM    256
#define NH    8
#define HDIM  32
#define NL    3
#define NP    4
#define NTOK  13125   // total value tokens per batch (10000+2500+625)

typedef __attribute__((ext_vector_type(8))) short bf16x8;   // 8 bf16 in 4 VGPRs
typedef __attribute__((ext_vector_type(4))) float f32x4;

__device__ __forceinline__ short f2bf(float f) {
    // round-to-nearest-even fp32 -> bf16
    unsigned u = __float_as_uint(f);
    unsigned r = (u + 0x7FFFu + ((u >> 16) & 1u)) >> 16;
    return (short)r;
}

// ---------------- weight prep: Wt[n][k] bf16  <-  W[k][n] fp32 (K=256 always) ----------------
__global__ __launch_bounds__(256) void wprep_kernel(const float* __restrict__ Wv,
                                                    const float* __restrict__ Wo,
                                                    const float* __restrict__ Wa,
                                                    const float* __restrict__ Wu,
                                                    short* __restrict__ Wt)
{
    const int w = blockIdx.y;
    const int Ns[4]   = {256, 192, 96, 256};
    const int Offs[4] = {0, 256 * 256, 256 * 256 + 192 * 256, 256 * 256 + 192 * 256 + 96 * 256};
    const float* W = (w == 0) ? Wv : ((w == 1) ? Wo : ((w == 2) ? Wa : Wu));
    const int N = Ns[w];
    const int flat = blockIdx.x * 256 + threadIdx.x;
    const int n = flat >> 8, k = flat & 255;
    if (n < N) Wt[Offs[w] + n * 256 + k] = f2bf(W[k * N + n]);
}

// ---------------- bf16 MFMA GEMM tile: C(MxN) = A(Mx256) @ W(256xN) + bias ----------------
// A fp32 row-major (K=256), Wt bf16 [N][256] (pre-transposed), C fp32 row-major.
// Block: 256 threads = 4 waves; tile 64(M)x64(N); wave -> 32x32 via 2x2 of 16x16x32 MFMA.
__device__ __forceinline__ void mfma_gemm_tile(const float* __restrict__ A,
                                               const short* __restrict__ Wt,
                                               const float* __restrict__ bias,
                                               float* __restrict__ C,
                                               int M, int N, int m0, int n0)
{
    __shared__ short As[64][40];   // [m][k] bf16, +8 pad
    __shared__ short Bs[64][40];   // [n][k] bf16, +8 pad

    const int tid  = threadIdx.x;
    const int lane = tid & 63;
    const int wave = tid >> 6;
    const int wm   = (wave & 1) * 32;
    const int wn   = (wave >> 1) * 32;
    const int ml   = lane & 15;    // m (or n) within 16-tile
    const int kq   = lane >> 4;    // quad 0..3

    const int srow = tid >> 2;          // 0..63 staging row
    const int skp  = (tid & 3) * 8;     // k part 0,8,16,24
    const bool aval = (m0 + srow) < M;
    const bool bval = (n0 + srow) < N;
    const float* Arow = A  + (size_t)(m0 + srow) * 256;
    const short* Wrow = Wt + (size_t)(n0 + srow) * 256;

    f32x4 acc[2][2] = {};

    for (int k0 = 0; k0 < 256; k0 += 32) {
        union { bf16x8 v; short s[8]; } ta;
        if (aval) {
            float4 a0 = *(const float4*)(Arow + k0 + skp);
            float4 a1 = *(const float4*)(Arow + k0 + skp + 4);
            ta.s[0] = f2bf(a0.x); ta.s[1] = f2bf(a0.y); ta.s[2] = f2bf(a0.z); ta.s[3] = f2bf(a0.w);
            ta.s[4] = f2bf(a1.x); ta.s[5] = f2bf(a1.y); ta.s[6] = f2bf(a1.z); ta.s[7] = f2bf(a1.w);
        } else {
#pragma unroll
            for (int i = 0; i < 8; ++i) ta.s[i] = 0;
        }
        *(bf16x8*)&As[srow][skp] = ta.v;

        union { bf16x8 v; short s[8]; } tb;
        if (bval) {
            tb.v = *(const bf16x8*)(Wrow + k0 + skp);
        } else {
#pragma unroll
            for (int i = 0; i < 8; ++i) tb.s[i] = 0;
        }
        *(bf16x8*)&Bs[srow][skp] = tb.v;

        __syncthreads();

        bf16x8 af0 = *(const bf16x8*)&As[wm + 0  + ml][kq * 8];
        bf16x8 af1 = *(const bf16x8*)&As[wm + 16 + ml][kq * 8];
        bf16x8 bf0 = *(const bf16x8*)&Bs[wn + 0  + ml][kq * 8];
        bf16x8 bf1 = *(const bf16x8*)&Bs[wn + 16 + ml][kq * 8];
        acc[0][0] = __builtin_amdgcn_mfma_f32_16x16x32_bf16(af0, bf0, acc[0][0], 0, 0, 0);
        acc[0][1] = __builtin_amdgcn_mfma_f32_16x16x32_bf16(af0, bf1, acc[0][1], 0, 0, 0);
        acc[1][0] = __builtin_amdgcn_mfma_f32_16x16x32_bf16(af1, bf0, acc[1][0], 0, 0, 0);
        acc[1][1] = __builtin_amdgcn_mfma_f32_16x16x32_bf16(af1, bf1, acc[1][1], 0, 0, 0);

        __syncthreads();
    }

    // C/D layout: col = lane&15, row = (lane>>4)*4 + reg   [measured m89/m91]
#pragma unroll
    for (int ti = 0; ti < 2; ++ti) {
#pragma unroll
        for (int tj = 0; tj < 2; ++tj) {
#pragma unroll
            for (int r = 0; r < 4; ++r) {
                const int gm = m0 + wm + ti * 16 + kq * 4 + r;
                const int gn = n0 + wn + tj * 16 + ml;
                if (gm < M && gn < N) C[(size_t)gm * N + gn] = acc[ti][tj][r] + bias[gn];
            }
        }
    }
}

__global__ __launch_bounds__(256) void qgemm_kernel(const float* __restrict__ A,
                                                    const short* __restrict__ Wt,
                                                    const float* __restrict__ bias,
                                                    float* __restrict__ C,
                                                    int M, int N)
{
    const int m0 = blockIdx.y * 64;
    const int n0 = blockIdx.x * 64;
    if (m0 >= M) return;
    mfma_gemm_tile(A, Wt, bias, C, M, N, m0, n0);
}

// value projection over all (batch, level) slices in one launch via grid.z
__global__ __launch_bounds__(256) void vproj_kernel(const float* __restrict__ v0,
                                                    const float* __restrict__ v1,
                                                    const float* __restrict__ v2,
                                                    const short* __restrict__ Wt,
                                                    const float* __restrict__ bias,
                                                    float* __restrict__ vws)
{
    const int z = blockIdx.z;          // 0..5 = b*3 + lvl
    const int b = z / 3, l = z % 3;
    const int Ms[3]   = {10000, 2500, 625};
    const int Offs[3] = {0, 10000, 12500};
    const float* Asel = (l == 0) ? v0 : ((l == 1) ? v1 : v2);
    const int M = Ms[l];
    const float* A = Asel + (size_t)b * M * DM;
    float* C = vws + ((size_t)b * NTOK + Offs[l]) * DM;
    const int m0 = blockIdx.y * 64;
    const int n0 = blockIdx.x * 64;
    if (m0 >= M) return;
    mfma_gemm_tile(A, Wt, bias, C, M, DM, m0, n0);
}

// ---------------- sampling: one block per (b, q); 256 threads = (head, channel) ----------------
__global__ __launch_bounds__(256) void sample_kernel(const float* __restrict__ vws,
                                                     const float* __restrict__ offs,
                                                     const float* __restrict__ logits,
                                                     const float* __restrict__ refp,
                                                     float* __restrict__ mid)
{
    const int q   = blockIdx.x;          // 0..B*NQ-1
    const int b   = q / NQ;
    const int tid = threadIdx.x;
    const int h   = tid >> 5;            // head
    const int hd  = tid & 31;            // channel within head

    __shared__ float s_off[NH * NL * NP * 2];   // 192
    __shared__ float s_lg[NH * NL * NP];        // 96
    __shared__ float s_ref[NL * 2];             // 6

    if (tid < 192) s_off[tid] = offs[(size_t)q * 192 + tid];
    if (tid < 96)  s_lg[tid]  = logits[(size_t)q * 96 + tid];
    if (tid < 6)   s_ref[tid] = refp[(size_t)q * 6 + tid];
    __syncthreads();

    // softmax over L*P = 12 per head (redundant across the 32 lanes of a head)
    float w[12];
    float mx = -1e30f;
#pragma unroll
    for (int i = 0; i < 12; ++i) { w[i] = s_lg[h * 12 + i]; mx = fmaxf(mx, w[i]); }
    float ssum = 0.f;
#pragma unroll
    for (int i = 0; i < 12; ++i) { w[i] = expf(w[i] - mx); ssum += w[i]; }
    const float inv = 1.f / ssum;

    const int Hs[3] = {100, 50, 25};
    const int Wz[3] = {100, 50, 25};
    const int Lo[3] = {0, 10000, 12500};

    float acc = 0.f;
#pragma unroll
    for (int l = 0; l < NL; ++l) {
        const int Wl = Wz[l], Hl = Hs[l];
        const float fW = (float)Wl, fH = (float)Hl;
        const float rx = s_ref[l * 2 + 0];
        const float ry = s_ref[l * 2 + 1];
        const float* vb = vws + ((size_t)b * NTOK + Lo[l]) * DM + h * HDIM + hd;
#pragma unroll
        for (int p = 0; p < NP; ++p) {
            const int oi = (((h * NL) + l) * NP + p) * 2;
            const float x = (rx + s_off[oi]     / fW) * fW - 0.5f;
            const float y = (ry + s_off[oi + 1] / fH) * fH - 0.5f;
            const float x0f = floorf(x), y0f = floorf(y);
            const int   x0 = (int)x0f,  y0 = (int)y0f;
            const float wx1 = x - x0f, wy1 = y - y0f;
            const float wx0 = 1.f - wx1, wy0 = 1.f - wy1;

            const bool xin0 = (x0 >= 0) && (x0 < Wl);
            const bool xin1 = (x0 + 1 >= 0) && (x0 + 1 < Wl);
            const bool yin0 = (y0 >= 0) && (y0 < Hl);
            const bool yin1 = (y0 + 1 >= 0) && (y0 + 1 < Hl);

            float sv = 0.f;
            if (xin0 && yin0) sv += wx0 * wy0 * vb[(size_t)(y0 * Wl + x0) * DM];
            if (xin1 && yin0) sv += wx1 * wy0 * vb[(size_t)(y0 * Wl + x0 + 1) * DM];
            if (xin0 && yin1) sv += wx0 * wy1 * vb[(size_t)((y0 + 1) * Wl + x0) * DM];
            if (xin1 && yin1) sv += wx1 * wy1 * vb[(size_t)((y0 + 1) * Wl + x0 + 1) * DM];

            acc += w[l * NP + p] * sv;
        }
    }
    mid[(size_t)q * DM + h * HDIM + hd] = acc * inv;
}

// ---------------------------------------------------------------------------------------------
extern "C" void kernel_launch(void* const* d_in, const int* in_sizes, int n_in,
                              void* d_out, int out_size, void* d_ws, size_t ws_size,
                              hipStream_t stream)
{
    const float* query  = (const float*)d_in[0];
    const float* refp   = (const float*)d_in[1];
    const float* v0     = (const float*)d_in[2];
    const float* v1     = (const float*)d_in[3];
    const float* v2     = (const float*)d_in[4];
    const float* W_val  = (const float*)d_in[5];
    const float* b_val  = (const float*)d_in[6];
    const float* W_off  = (const float*)d_in[7];
    const float* b_off  = (const float*)d_in[8];
    const float* W_attn = (const float*)d_in[9];
    const float* b_attn = (const float*)d_in[10];
    const float* W_out  = (const float*)d_in[11];
    const float* b_out  = (const float*)d_in[12];
    float* out = (float*)d_out;

    float* ws   = (float*)d_ws;
    float* vws  = ws;                                   // 2*13125*256 f32
    float* offs = vws  + (size_t)BATCH * NTOK * DM;     // 2*13125*192 f32
    float* lgts = offs + (size_t)BATCH * NQ * 192;      // 2*13125*96  f32
    float* mid  = lgts + (size_t)BATCH * NQ * 96;       // 2*13125*256 f32
    short* Wt   = (short*)(mid + (size_t)BATCH * NQ * DM);  // 204800 bf16
    short* Wt_val  = Wt;
    short* Wt_off  = Wt_val + 256 * 256;
    short* Wt_attn = Wt_off + 192 * 256;
    short* Wt_out  = Wt_attn + 96 * 256;

    const int Mq = BATCH * NQ;   // 26250

    // 0. weight transpose + bf16 convert
    {
        dim3 grid(256, 4);
        wprep_kernel<<<grid, 256, 0, stream>>>(W_val, W_off, W_attn, W_out, Wt);
    }
    // 1. value projection (all 6 batch/level slices)
    {
        dim3 grid(DM / 64, (10000 + 63) / 64, 6);
        vproj_kernel<<<grid, 256, 0, stream>>>(v0, v1, v2, Wt_val, b_val, vws);
    }
    // 2. sampling offsets: query @ W_off + b_off
    {
        dim3 grid(192 / 64, (Mq + 63) / 64);
        qgemm_kernel<<<grid, 256, 0, stream>>>(query, Wt_off, b_off, offs, Mq, 192);
    }
    // 3. attention logits: query @ W_attn + b_attn
    {
        dim3 grid((96 + 63) / 64, (Mq + 63) / 64);
        qgemm_kernel<<<grid, 256, 0, stream>>>(query, Wt_attn, b_attn, lgts, Mq, 96);
    }
    // 4. softmax + bilinear sampling + head-weighted accumulation
    sample_kernel<<<Mq, 256, 0, stream>>>(vws, offs, lgts, refp, mid);
    // 5. output projection
    {
        dim3 grid(DM / 64, (Mq + 63) / 64);
        qgemm_kernel<<<grid, 256, 0, stream>>>(mid, Wt_out, b_out, out, Mq, DM);
    }
}

// Round 3
// 287.746 us; speedup vs baseline: 1.8709x; 1.4773x over previous
//
#include <hip/hip_runtime.h>
#include <hip/hip_bf16.h>
#include <math.h>

#define BATCH 2
#define NQ    13125
#define DM    256
#define NH    8
#define HDIM  32
#define NL    3
#define NP    4
#define NTOK  13125   // total value tokens per batch (10000+2500+625)

typedef __attribute__((ext_vector_type(8))) short bf16x8;   // 8 bf16 in 4 VGPRs
typedef __attribute__((ext_vector_type(4))) float f32x4;

__device__ __forceinline__ short f2bf(float f) {
    unsigned u = __float_as_uint(f);
    unsigned r = (u + 0x7FFFu + ((u >> 16) & 1u)) >> 16;
    return (short)r;
}

// ---------------- weight prep: Wt[n][k] bf16  <-  W[k][n] fp32 (K=256 always) ----------------
__global__ __launch_bounds__(256) void wprep_kernel(const float* __restrict__ Wv,
                                                    const float* __restrict__ Wo,
                                                    const float* __restrict__ Wa,
                                                    const float* __restrict__ Wu,
                                                    short* __restrict__ Wt)
{
    const int w = blockIdx.y;
    const int Ns[4]   = {256, 192, 96, 256};
    const int Offs[4] = {0, 256 * 256, 256 * 256 + 192 * 256, 256 * 256 + 192 * 256 + 96 * 256};
    const float* W = (w == 0) ? Wv : ((w == 1) ? Wo : ((w == 2) ? Wa : Wu));
    const int N = Ns[w];
    const int flat = blockIdx.x * 256 + threadIdx.x;
    const int n = flat >> 8, k = flat & 255;
    if (n < N) Wt[Offs[w] + n * 256 + k] = f2bf(W[k * N + n]);
}

// ---------------- bf16 MFMA GEMM tile: C(MxN) = A(Mx256) @ W(256xN) + bias ----------------
__device__ __forceinline__ void mfma_gemm_tile(const float* __restrict__ A,
                                               const short* __restrict__ Wt,
                                               const float* __restrict__ bias,
                                               float* __restrict__ C,
                                               int M, int N, int m0, int n0)
{
    __shared__ short As[64][40];
    __shared__ short Bs[64][40];

    const int tid  = threadIdx.x;
    const int lane = tid & 63;
    const int wave = tid >> 6;
    const int wm   = (wave & 1) * 32;
    const int wn   = (wave >> 1) * 32;
    const int ml   = lane & 15;
    const int kq   = lane >> 4;

    const int srow = tid >> 2;
    const int skp  = (tid & 3) * 8;
    const bool aval = (m0 + srow) < M;
    const bool bval = (n0 + srow) < N;
    const float* Arow = A  + (size_t)(m0 + srow) * 256;
    const short* Wrow = Wt + (size_t)(n0 + srow) * 256;

    f32x4 acc[2][2] = {};

    for (int k0 = 0; k0 < 256; k0 += 32) {
        union { bf16x8 v; short s[8]; } ta;
        if (aval) {
            float4 a0 = *(const float4*)(Arow + k0 + skp);
            float4 a1 = *(const float4*)(Arow + k0 + skp + 4);
            ta.s[0] = f2bf(a0.x); ta.s[1] = f2bf(a0.y); ta.s[2] = f2bf(a0.z); ta.s[3] = f2bf(a0.w);
            ta.s[4] = f2bf(a1.x); ta.s[5] = f2bf(a1.y); ta.s[6] = f2bf(a1.z); ta.s[7] = f2bf(a1.w);
        } else {
#pragma unroll
            for (int i = 0; i < 8; ++i) ta.s[i] = 0;
        }
        *(bf16x8*)&As[srow][skp] = ta.v;

        union { bf16x8 v; short s[8]; } tb;
        if (bval) {
            tb.v = *(const bf16x8*)(Wrow + k0 + skp);
        } else {
#pragma unroll
            for (int i = 0; i < 8; ++i) tb.s[i] = 0;
        }
        *(bf16x8*)&Bs[srow][skp] = tb.v;

        __syncthreads();

        bf16x8 af0 = *(const bf16x8*)&As[wm + 0  + ml][kq * 8];
        bf16x8 af1 = *(const bf16x8*)&As[wm + 16 + ml][kq * 8];
        bf16x8 bf0 = *(const bf16x8*)&Bs[wn + 0  + ml][kq * 8];
        bf16x8 bf1 = *(const bf16x8*)&Bs[wn + 16 + ml][kq * 8];
        acc[0][0] = __builtin_amdgcn_mfma_f32_16x16x32_bf16(af0, bf0, acc[0][0], 0, 0, 0);
        acc[0][1] = __builtin_amdgcn_mfma_f32_16x16x32_bf16(af0, bf1, acc[0][1], 0, 0, 0);
        acc[1][0] = __builtin_amdgcn_mfma_f32_16x16x32_bf16(af1, bf0, acc[1][0], 0, 0, 0);
        acc[1][1] = __builtin_amdgcn_mfma_f32_16x16x32_bf16(af1, bf1, acc[1][1], 0, 0, 0);

        __syncthreads();
    }

#pragma unroll
    for (int ti = 0; ti < 2; ++ti) {
#pragma unroll
        for (int tj = 0; tj < 2; ++tj) {
#pragma unroll
            for (int r = 0; r < 4; ++r) {
                const int gm = m0 + wm + ti * 16 + kq * 4 + r;
                const int gn = n0 + wn + tj * 16 + ml;
                if (gm < M && gn < N) C[(size_t)gm * N + gn] = acc[ti][tj][r] + bias[gn];
            }
        }
    }
}

__global__ __launch_bounds__(256) void qgemm_kernel(const float* __restrict__ A,
                                                    const short* __restrict__ Wt,
                                                    const float* __restrict__ bias,
                                                    float* __restrict__ C,
                                                    int M, int N)
{
    const int m0 = blockIdx.y * 64;
    const int n0 = blockIdx.x * 64;
    if (m0 >= M) return;
    mfma_gemm_tile(A, Wt, bias, C, M, N, m0, n0);
}

__global__ __launch_bounds__(256) void vproj_kernel(const float* __restrict__ v0,
                                                    const float* __restrict__ v1,
                                                    const float* __restrict__ v2,
                                                    const short* __restrict__ Wt,
                                                    const float* __restrict__ bias,
                                                    float* __restrict__ vws)
{
    const int z = blockIdx.z;
    const int b = z / 3, l = z % 3;
    const int Ms[3]   = {10000, 2500, 625};
    const int Offs[3] = {0, 10000, 12500};
    const float* Asel = (l == 0) ? v0 : ((l == 1) ? v1 : v2);
    const int M = Ms[l];
    const float* A = Asel + (size_t)b * M * DM;
    float* C = vws + ((size_t)b * NTOK + Offs[l]) * DM;
    const int m0 = blockIdx.y * 64;
    const int n0 = blockIdx.x * 64;
    if (m0 >= M) return;
    mfma_gemm_tile(A, Wt, bias, C, M, DM, m0, n0);
}

// ---------------- sampling: one block per 2 queries ----------------
// Phase A: stage logits/ref; Phase B: per-head softmax stats (16 thr);
// Phase C: 96 samples/query computed once -> folded corner weights + token idx in LDS;
// Phase D: gather-FMA, 128 threads/query = (head, 16 lanes x float2 channels).
__global__ __launch_bounds__(256) void sample_kernel(const float* __restrict__ vws,
                                                     const float* __restrict__ offs,
                                                     const float* __restrict__ logits,
                                                     const float* __restrict__ refp,
                                                     float* __restrict__ mid)
{
    const int q0  = blockIdx.x * 2;      // first global query (b*NQ+q flattened)
    const int tid = threadIdx.x;

    __shared__ float  s_lg[2][96];
    __shared__ float  s_ref[2][6];
    __shared__ float  s_stat[2][NH][2];  // [mx, inv]
    __shared__ float4 s_w[2][96];
    __shared__ int4   s_i[2][96];

    // ---- Phase A: stage logits + ref ----
    if (tid < 192) {
        const int qq = tid / 96, s = tid % 96;
        s_lg[qq][s] = logits[(size_t)(q0 + qq) * 96 + s];
    } else if (tid < 204) {
        const int t = tid - 192, qq = t / 6, j = t % 6;
        s_ref[qq][j] = refp[(size_t)(q0 + qq) * 6 + j];
    }
    __syncthreads();

    // ---- Phase B: per-head softmax stats ----
    if (tid < 16) {
        const int qq = tid >> 3, h = tid & 7;
        float mx = -1e30f;
#pragma unroll
        for (int i = 0; i < 12; ++i) mx = fmaxf(mx, s_lg[qq][h * 12 + i]);
        float ssum = 0.f;
#pragma unroll
        for (int i = 0; i < 12; ++i) ssum += expf(s_lg[qq][h * 12 + i] - mx);
        s_stat[qq][h][0] = mx;
        s_stat[qq][h][1] = 1.f / ssum;
    }
    __syncthreads();

    // ---- Phase C: per-sample weights + indices ----
    if (tid < 192) {
        const int qq = tid / 96, s = tid % 96;
        const int q  = q0 + qq;
        const int b  = q / NQ;
        const int h  = s / 12, i = s % 12;
        const int l  = i >> 2, p = i & 3;

        const int Hs[3] = {100, 50, 25};
        const int Wz[3] = {100, 50, 25};
        const int Lo[3] = {0, 10000, 12500};
        const int Wl = Wz[l], Hl = Hs[l];
        const float fW = (float)Wl, fH = (float)Hl;

        const float aw = expf(s_lg[qq][s] - s_stat[qq][h][0]) * s_stat[qq][h][1];

        const int oi = (((h * NL) + l) * NP + p) * 2;
        const float2 offp = *(const float2*)(offs + (size_t)q * 192 + oi);
        const float rx = s_ref[qq][l * 2 + 0];
        const float ry = s_ref[qq][l * 2 + 1];

        const float x = (rx + offp.x / fW) * fW - 0.5f;
        const float y = (ry + offp.y / fH) * fH - 0.5f;
        const float x0f = floorf(x), y0f = floorf(y);
        const int   x0 = (int)x0f,  y0 = (int)y0f;
        const float wx1 = x - x0f, wy1 = y - y0f;
        const float wx0 = 1.f - wx1, wy0 = 1.f - wy1;

        const bool xin0 = (x0 >= 0) && (x0 < Wl);
        const bool xin1 = (x0 + 1 >= 0) && (x0 + 1 < Wl);
        const bool yin0 = (y0 >= 0) && (y0 < Hl);
        const bool yin1 = (y0 + 1 >= 0) && (y0 + 1 < Hl);

        const int cx0 = min(max(x0, 0), Wl - 1);
        const int cx1 = min(max(x0 + 1, 0), Wl - 1);
        const int cy0 = min(max(y0, 0), Hl - 1);
        const int cy1 = min(max(y0 + 1, 0), Hl - 1);

        const int base = b * NTOK + Lo[l];
        int4 idx;
        idx.x = base + cy0 * Wl + cx0;
        idx.y = base + cy0 * Wl + cx1;
        idx.z = base + cy1 * Wl + cx0;
        idx.w = base + cy1 * Wl + cx1;

        float4 w;
        w.x = (xin0 && yin0) ? aw * wx0 * wy0 : 0.f;
        w.y = (xin1 && yin0) ? aw * wx1 * wy0 : 0.f;
        w.z = (xin0 && yin1) ? aw * wx0 * wy1 : 0.f;
        w.w = (xin1 && yin1) ? aw * wx1 * wy1 : 0.f;

        s_w[qq][s] = w;
        s_i[qq][s] = idx;
    }
    __syncthreads();

    // ---- Phase D: gather-FMA ----
    {
        const int qq = tid >> 7;             // 0/1
        const int r  = tid & 127;
        const int h  = r >> 4;               // head
        const int c2 = (r & 15) * 2;         // channel pair
        const int ch = h * HDIM + c2;

        float ax = 0.f, ay = 0.f;
#pragma unroll
        for (int s = 0; s < 12; ++s) {
            const float4 w  = s_w[qq][h * 12 + s];
            const int4   id = s_i[qq][h * 12 + s];
            const float2 v0 = *(const float2*)(vws + (size_t)id.x * DM + ch);
            const float2 v1 = *(const float2*)(vws + (size_t)id.y * DM + ch);
            const float2 v2 = *(const float2*)(vws + (size_t)id.z * DM + ch);
            const float2 v3 = *(const float2*)(vws + (size_t)id.w * DM + ch);
            ax += w.x * v0.x + w.y * v1.x + w.z * v2.x + w.w * v3.x;
            ay += w.x * v0.y + w.y * v1.y + w.z * v2.y + w.w * v3.y;
        }
        float2* o = (float2*)(mid + (size_t)(q0 + qq) * DM + ch);
        *o = make_float2(ax, ay);
    }
}

// ---------------------------------------------------------------------------------------------
extern "C" void kernel_launch(void* const* d_in, const int* in_sizes, int n_in,
                              void* d_out, int out_size, void* d_ws, size_t ws_size,
                              hipStream_t stream)
{
    const float* query  = (const float*)d_in[0];
    const float* refp   = (const float*)d_in[1];
    const float* v0     = (const float*)d_in[2];
    const float* v1     = (const float*)d_in[3];
    const float* v2     = (const float*)d_in[4];
    const float* W_val  = (const float*)d_in[5];
    const float* b_val  = (const float*)d_in[6];
    const float* W_off  = (const float*)d_in[7];
    const float* b_off  = (const float*)d_in[8];
    const float* W_attn = (const float*)d_in[9];
    const float* b_attn = (const float*)d_in[10];
    const float* W_out  = (const float*)d_in[11];
    const float* b_out  = (const float*)d_in[12];
    float* out = (float*)d_out;

    float* ws   = (float*)d_ws;
    float* vws  = ws;                                   // 2*13125*256 f32
    float* offs = vws  + (size_t)BATCH * NTOK * DM;     // 2*13125*192 f32
    float* lgts = offs + (size_t)BATCH * NQ * 192;      // 2*13125*96  f32
    float* mid  = lgts + (size_t)BATCH * NQ * 96;       // 2*13125*256 f32
    short* Wt   = (short*)(mid + (size_t)BATCH * NQ * DM);
    short* Wt_val  = Wt;
    short* Wt_off  = Wt_val + 256 * 256;
    short* Wt_attn = Wt_off + 192 * 256;
    short* Wt_out  = Wt_attn + 96 * 256;

    const int Mq = BATCH * NQ;   // 26250

    // 0. weight transpose + bf16 convert
    {
        dim3 grid(256, 4);
        wprep_kernel<<<grid, 256, 0, stream>>>(W_val, W_off, W_attn, W_out, Wt);
    }
    // 1. value projection
    {
        dim3 grid(DM / 64, (10000 + 63) / 64, 6);
        vproj_kernel<<<grid, 256, 0, stream>>>(v0, v1, v2, Wt_val, b_val, vws);
    }
    // 2. sampling offsets
    {
        dim3 grid(192 / 64, (Mq + 63) / 64);
        qgemm_kernel<<<grid, 256, 0, stream>>>(query, Wt_off, b_off, offs, Mq, 192);
    }
    // 3. attention logits
    {
        dim3 grid((96 + 63) / 64, (Mq + 63) / 64);
        qgemm_kernel<<<grid, 256, 0, stream>>>(query, Wt_attn, b_attn, lgts, Mq, 96);
    }
    // 4. softmax + bilinear sampling (2 queries per block)
    sample_kernel<<<Mq / 2, 256, 0, stream>>>(vws, offs, lgts, refp, mid);
    // 5. output projection
    {
        dim3 grid(DM / 64, (Mq + 63) / 64);
        qgemm_kernel<<<grid, 256, 0, stream>>>(mid, Wt_out, b_out, out, Mq, DM);
    }
}

// Round 4
// 240.852 us; speedup vs baseline: 2.2351x; 1.1947x over previous
//
#include <hip/hip_runtime.h>
#include <hip/hip_bf16.h>
#include <math.h>

#define BATCH 2
#define NQ    13125
#define MQ    26250   // BATCH*NQ
#define DM    256
#define NH    8
#define HDIM  32
#define NL    3
#define NP    4
#define NTOK  13125   // total value tokens per batch (10000+2500+625)

typedef __attribute__((ext_vector_type(8))) short bf16x8;   // 8 bf16 in 4 VGPRs
typedef __attribute__((ext_vector_type(4))) float f32x4;

__device__ __forceinline__ short f2bf(float f) {
    unsigned u = __float_as_uint(f);
    unsigned r = (u + 0x7FFFu + ((u >> 16) & 1u)) >> 16;
    return (short)r;
}
__device__ __forceinline__ float bf2f(unsigned short u) {
    return __uint_as_float((unsigned)u << 16);
}

// ---------------- weight prep: Wt[n][k] bf16  <-  W[k][n] fp32 (K=256 always) ----------------
__global__ __launch_bounds__(256) void wprep_kernel(const float* __restrict__ Wv,
                                                    const float* __restrict__ Wo,
                                                    const float* __restrict__ Wa,
                                                    const float* __restrict__ Wu,
                                                    short* __restrict__ Wt)
{
    const int w = blockIdx.y;
    const int Ns[4]   = {256, 192, 96, 256};
    const int Offs[4] = {0, 256 * 256, 256 * 256 + 192 * 256, 256 * 256 + 192 * 256 + 96 * 256};
    const float* W = (w == 0) ? Wv : ((w == 1) ? Wo : ((w == 2) ? Wa : Wu));
    const int N = Ns[w];
    const int flat = blockIdx.x * 256 + threadIdx.x;
    const int n = flat >> 8, k = flat & 255;
    if (n < N) Wt[Offs[w] + n * 256 + k] = f2bf(W[k * N + n]);
}

// ---------------- activation convert fp32 -> bf16 (query, v0, v1, v2) ----------------
__global__ __launch_bounds__(256) void cvt_kernel(const float* __restrict__ q,
                                                  const float* __restrict__ v0,
                                                  const float* __restrict__ v1,
                                                  const float* __restrict__ v2,
                                                  short* __restrict__ qb,
                                                  short* __restrict__ v0b,
                                                  short* __restrict__ v1b,
                                                  short* __restrict__ v2b)
{
    const int t = blockIdx.y;
    const int sz4[4] = {MQ * 64, 2 * 10000 * 64, 2 * 2500 * 64, 2 * 625 * 64}; // float4 units
    const float* src = (t == 0) ? q : ((t == 1) ? v0 : ((t == 2) ? v1 : v2));
    short* dst = (t == 0) ? qb : ((t == 1) ? v0b : ((t == 2) ? v1b : v2b));
    const int i = blockIdx.x * 256 + threadIdx.x;
    if (i < sz4[t]) {
        float4 v = ((const float4*)src)[i];
        short4 o;
        o.x = f2bf(v.x); o.y = f2bf(v.y); o.z = f2bf(v.z); o.w = f2bf(v.w);
        ((short4*)dst)[i] = o;
    }
}

// ---------------- bf16 MFMA GEMM tile 128(M)x64(N), K=256, A bf16 [M][256], Wt bf16 [N][256] --
// EPI: 0 = fp32 C (C0, bias0, width N), 1 = bf16 C, 2 = split offs(192)/lgts(96)
template<int EPI>
__device__ __forceinline__ void gemm_body(const short* __restrict__ A,
                                          const short* __restrict__ Wt,
                                          const float* __restrict__ bias0,
                                          const float* __restrict__ bias1,
                                          void* __restrict__ C0,
                                          void* __restrict__ C1,
                                          int M, int N, int m0, int n0)
{
    __shared__ short As[128][40];
    __shared__ short Bs[64][40];

    const int tid  = threadIdx.x;
    const int lane = tid & 63;
    const int wave = tid >> 6;
    const int wm   = wave * 32;
    const int ml   = lane & 15;
    const int kq   = lane >> 4;

    const int srow = tid >> 2;          // 0..63
    const int skp  = (tid & 3) * 8;     // 0,8,16,24

    f32x4 acc[2][4] = {};

    for (int k0 = 0; k0 < 256; k0 += 32) {
#pragma unroll
        for (int rr = 0; rr < 2; ++rr) {
            const int row = srow + rr * 64;
            bf16x8 t = {};
            if (m0 + row < M) t = *(const bf16x8*)(A + (size_t)(m0 + row) * 256 + k0 + skp);
            *(bf16x8*)&As[row][skp] = t;
        }
        {
            bf16x8 t = {};
            if (n0 + srow < N) t = *(const bf16x8*)(Wt + (size_t)(n0 + srow) * 256 + k0 + skp);
            *(bf16x8*)&Bs[srow][skp] = t;
        }
        __syncthreads();

        bf16x8 af[2], bfr[4];
#pragma unroll
        for (int ti = 0; ti < 2; ++ti) af[ti] = *(const bf16x8*)&As[wm + ti * 16 + ml][kq * 8];
#pragma unroll
        for (int tj = 0; tj < 4; ++tj) bfr[tj] = *(const bf16x8*)&Bs[tj * 16 + ml][kq * 8];
#pragma unroll
        for (int ti = 0; ti < 2; ++ti)
#pragma unroll
            for (int tj = 0; tj < 4; ++tj)
                acc[ti][tj] = __builtin_amdgcn_mfma_f32_16x16x32_bf16(af[ti], bfr[tj], acc[ti][tj], 0, 0, 0);

        __syncthreads();
    }

    // C/D layout: col = lane&15, row = (lane>>4)*4 + reg
#pragma unroll
    for (int ti = 0; ti < 2; ++ti) {
#pragma unroll
        for (int tj = 0; tj < 4; ++tj) {
#pragma unroll
            for (int r = 0; r < 4; ++r) {
                const int gm = m0 + wm + ti * 16 + kq * 4 + r;
                const int gn = n0 + tj * 16 + ml;
                if (gm >= M || gn >= N) continue;
                if (EPI == 0) {
                    ((float*)C0)[(size_t)gm * N + gn] = acc[ti][tj][r] + bias0[gn];
                } else if (EPI == 1) {
                    ((short*)C0)[(size_t)gm * N + gn] = f2bf(acc[ti][tj][r] + bias0[gn]);
                } else {
                    if (gn < 192) ((float*)C0)[(size_t)gm * 192 + gn] = acc[ti][tj][r] + bias0[gn];
                    else          ((float*)C1)[(size_t)gm * 96 + gn - 192] = acc[ti][tj][r] + bias1[gn - 192];
                }
            }
        }
    }
}

// fused offsets+logits: A=qbf, Wt rows 0..287 = [W_off | W_attn]
__global__ __launch_bounds__(256) void qgemm_fused_kernel(const short* __restrict__ A,
                                                          const short* __restrict__ Wt,
                                                          const float* __restrict__ b_off,
                                                          const float* __restrict__ b_attn,
                                                          float* __restrict__ offs,
                                                          float* __restrict__ lgts)
{
    const int m0 = blockIdx.y * 128;
    const int n0 = blockIdx.x * 64;
    gemm_body<2>(A, Wt, b_off, b_attn, offs, lgts, MQ, 288, m0, n0);
}

// output projection: A=mid(bf16), C=out(fp32)
__global__ __launch_bounds__(256) void ogemm_kernel(const short* __restrict__ A,
                                                    const short* __restrict__ Wt,
                                                    const float* __restrict__ bias,
                                                    float* __restrict__ C)
{
    const int m0 = blockIdx.y * 128;
    const int n0 = blockIdx.x * 64;
    gemm_body<0>(A, Wt, bias, nullptr, C, nullptr, MQ, DM, m0, n0);
}

// value projection -> vws bf16
__global__ __launch_bounds__(256) void vproj_kernel(const short* __restrict__ v0b,
                                                    const short* __restrict__ v1b,
                                                    const short* __restrict__ v2b,
                                                    const short* __restrict__ Wt,
                                                    const float* __restrict__ bias,
                                                    short* __restrict__ vws)
{
    const int z = blockIdx.z;
    const int b = z / 3, l = z % 3;
    const int Ms[3]   = {10000, 2500, 625};
    const int Offs[3] = {0, 10000, 12500};
    const short* Asel = (l == 0) ? v0b : ((l == 1) ? v1b : v2b);
    const int M = Ms[l];
    const short* A = Asel + (size_t)b * M * DM;
    short* C = vws + ((size_t)b * NTOK + Offs[l]) * DM;
    const int m0 = blockIdx.y * 128;
    const int n0 = blockIdx.x * 64;
    if (m0 >= M) return;
    gemm_body<1>(A, Wt, bias, nullptr, C, nullptr, M, DM, m0, n0);
}

// ---------------- sampling: one block per 4 queries, bf16 value/mid ----------------
__global__ __launch_bounds__(256) void sample_kernel(const short* __restrict__ vws,
                                                     const float* __restrict__ offs,
                                                     const float* __restrict__ logits,
                                                     const float* __restrict__ refp,
                                                     short* __restrict__ mid)
{
    const int q0  = blockIdx.x * 4;
    const int tid = threadIdx.x;

    __shared__ float  s_lg[4][96];
    __shared__ float  s_ref[4][6];
    __shared__ float  s_stat[4][NH][2];
    __shared__ float4 s_w[4][96];
    __shared__ int4   s_i[4][96];

    // ---- Phase A: stage logits + ref ----
    for (int idx = tid; idx < 384; idx += 256) {
        const int qq = idx / 96, s = idx % 96;
        const int q = q0 + qq;
        if (q < MQ) s_lg[qq][s] = logits[(size_t)q * 96 + s];
    }
    if (tid < 24) {
        const int qq = tid / 6, j = tid % 6;
        const int q = q0 + qq;
        if (q < MQ) s_ref[qq][j] = refp[(size_t)q * 6 + j];
    }
    __syncthreads();

    // ---- Phase B: per-head softmax stats ----
    if (tid < 32) {
        const int qq = tid >> 3, h = tid & 7;
        if (q0 + qq < MQ) {
            float mx = -1e30f;
#pragma unroll
            for (int i = 0; i < 12; ++i) mx = fmaxf(mx, s_lg[qq][h * 12 + i]);
            float ssum = 0.f;
#pragma unroll
            for (int i = 0; i < 12; ++i) ssum += expf(s_lg[qq][h * 12 + i] - mx);
            s_stat[qq][h][0] = mx;
            s_stat[qq][h][1] = 1.f / ssum;
        }
    }
    __syncthreads();

    // ---- Phase C: per-sample folded weights + token indices ----
    for (int idx = tid; idx < 384; idx += 256) {
        const int qq = idx / 96, s = idx % 96;
        const int q  = q0 + qq;
        if (q >= MQ) continue;
        const int b  = q / NQ;
        const int h  = s / 12, i = s % 12;
        const int l  = i >> 2, p = i & 3;

        const int Hs[3] = {100, 50, 25};
        const int Wz[3] = {100, 50, 25};
        const int Lo[3] = {0, 10000, 12500};
        const int Wl = Wz[l], Hl = Hs[l];
        const float fW = (float)Wl, fH = (float)Hl;

        const float aw = expf(s_lg[qq][s] - s_stat[qq][h][0]) * s_stat[qq][h][1];

        const int oi = (((h * NL) + l) * NP + p) * 2;
        const float2 offp = *(const float2*)(offs + (size_t)q * 192 + oi);
        const float rx = s_ref[qq][l * 2 + 0];
        const float ry = s_ref[qq][l * 2 + 1];

        const float x = (rx + offp.x / fW) * fW - 0.5f;
        const float y = (ry + offp.y / fH) * fH - 0.5f;
        const float x0f = floorf(x), y0f = floorf(y);
        const int   x0 = (int)x0f,  y0 = (int)y0f;
        const float wx1 = x - x0f, wy1 = y - y0f;
        const float wx0 = 1.f - wx1, wy0 = 1.f - wy1;

        const bool xin0 = (x0 >= 0) && (x0 < Wl);
        const bool xin1 = (x0 + 1 >= 0) && (x0 + 1 < Wl);
        const bool yin0 = (y0 >= 0) && (y0 < Hl);
        const bool yin1 = (y0 + 1 >= 0) && (y0 + 1 < Hl);

        const int cx0 = min(max(x0, 0), Wl - 1);
        const int cx1 = min(max(x0 + 1, 0), Wl - 1);
        const int cy0 = min(max(y0, 0), Hl - 1);
        const int cy1 = min(max(y0 + 1, 0), Hl - 1);

        const int base = b * NTOK + Lo[l];
        int4 idxv;
        idxv.x = base + cy0 * Wl + cx0;
        idxv.y = base + cy0 * Wl + cx1;
        idxv.z = base + cy1 * Wl + cx0;
        idxv.w = base + cy1 * Wl + cx1;

        float4 w;
        w.x = (xin0 && yin0) ? aw * wx0 * wy0 : 0.f;
        w.y = (xin1 && yin0) ? aw * wx1 * wy0 : 0.f;
        w.z = (xin0 && yin1) ? aw * wx0 * wy1 : 0.f;
        w.w = (xin1 && yin1) ? aw * wx1 * wy1 : 0.f;

        s_w[qq][s] = w;
        s_i[qq][s] = idxv;
    }
    __syncthreads();

    // ---- Phase D: gather-FMA, 64 threads/query, 4 bf16 channels per lane ----
    {
        const int qq = tid >> 6;
        const int q  = q0 + qq;
        if (q < MQ) {
            const int r  = tid & 63;
            const int h  = r >> 3;
            const int c4 = (r & 7) * 4;
            const int ch = h * HDIM + c4;

            float a0 = 0.f, a1 = 0.f, a2 = 0.f, a3 = 0.f;
#pragma unroll
            for (int s = 0; s < 12; ++s) {
                const float4 w  = s_w[qq][h * 12 + s];
                const int4   id = s_i[qq][h * 12 + s];
                const ushort4 u0 = *(const ushort4*)(vws + (size_t)id.x * DM + ch);
                const ushort4 u1 = *(const ushort4*)(vws + (size_t)id.y * DM + ch);
                const ushort4 u2 = *(const ushort4*)(vws + (size_t)id.z * DM + ch);
                const ushort4 u3 = *(const ushort4*)(vws + (size_t)id.w * DM + ch);
                a0 += w.x * bf2f(u0.x) + w.y * bf2f(u1.x) + w.z * bf2f(u2.x) + w.w * bf2f(u3.x);
                a1 += w.x * bf2f(u0.y) + w.y * bf2f(u1.y) + w.z * bf2f(u2.y) + w.w * bf2f(u3.y);
                a2 += w.x * bf2f(u0.z) + w.y * bf2f(u1.z) + w.z * bf2f(u2.z) + w.w * bf2f(u3.z);
                a3 += w.x * bf2f(u0.w) + w.y * bf2f(u1.w) + w.z * bf2f(u2.w) + w.w * bf2f(u3.w);
            }
            short4 o;
            o.x = f2bf(a0); o.y = f2bf(a1); o.z = f2bf(a2); o.w = f2bf(a3);
            *(short4*)(mid + (size_t)q * DM + ch) = o;
        }
    }
}

// ---------------------------------------------------------------------------------------------
extern "C" void kernel_launch(void* const* d_in, const int* in_sizes, int n_in,
                              void* d_out, int out_size, void* d_ws, size_t ws_size,
                              hipStream_t stream)
{
    const float* query  = (const float*)d_in[0];
    const float* refp   = (const float*)d_in[1];
    const float* v0     = (const float*)d_in[2];
    const float* v1     = (const float*)d_in[3];
    const float* v2     = (const float*)d_in[4];
    const float* W_val  = (const float*)d_in[5];
    const float* b_val  = (const float*)d_in[6];
    const float* W_off  = (const float*)d_in[7];
    const float* b_off  = (const float*)d_in[8];
    const float* W_attn = (const float*)d_in[9];
    const float* b_attn = (const float*)d_in[10];
    const float* W_out  = (const float*)d_in[11];
    const float* b_out  = (const float*)d_in[12];
    float* out = (float*)d_out;

    // workspace layout (all 16B-aligned)
    float* ws   = (float*)d_ws;
    float* offs = ws;                                    // MQ*192 f32
    float* lgts = offs + (size_t)MQ * 192;               // MQ*96 f32
    short* vws  = (short*)(lgts + (size_t)MQ * 96);      // 2*NTOK*256 bf16
    short* mid  = vws + (size_t)BATCH * NTOK * DM;       // MQ*256 bf16
    short* qbf  = mid + (size_t)MQ * DM;                 // MQ*256 bf16
    short* v0b  = qbf + (size_t)MQ * DM;                 // 2*10000*256 bf16
    short* v1b  = v0b + (size_t)2 * 10000 * DM;          // 2*2500*256 bf16
    short* v2b  = v1b + (size_t)2 * 2500 * DM;           // 2*625*256 bf16
    short* Wt   = v2b + (size_t)2 * 625 * DM;            // 204800 bf16
    short* Wt_val  = Wt;
    short* Wt_off  = Wt_val + 256 * 256;                 // fused [W_off|W_attn] = 288 rows
    short* Wt_out  = Wt_off + 288 * 256;

    // 0a. weight transpose + bf16 convert
    {
        dim3 grid(256, 4);
        wprep_kernel<<<grid, 256, 0, stream>>>(W_val, W_off, W_attn, W_out, Wt);
    }
    // 0b. activation fp32 -> bf16
    {
        dim3 grid((MQ * 64 + 255) / 256, 4);
        cvt_kernel<<<grid, 256, 0, stream>>>(query, v0, v1, v2, qbf, v0b, v1b, v2b);
    }
    // 1. value projection -> vws (bf16)
    {
        dim3 grid(DM / 64, (10000 + 127) / 128, 6);
        vproj_kernel<<<grid, 256, 0, stream>>>(v0b, v1b, v2b, Wt_val, b_val, vws);
    }
    // 2. fused offsets+logits
    {
        dim3 grid((288 + 63) / 64, (MQ + 127) / 128);
        qgemm_fused_kernel<<<grid, 256, 0, stream>>>(qbf, Wt_off, b_off, b_attn, offs, lgts);
    }
    // 3. softmax + bilinear sampling (4 queries/block) -> mid (bf16)
    sample_kernel<<<(MQ + 3) / 4, 256, 0, stream>>>(vws, offs, lgts, refp, mid);
    // 4. output projection
    {
        dim3 grid(DM / 64, (MQ + 127) / 128);
        ogemm_kernel<<<grid, 256, 0, stream>>>(mid, Wt_out, b_out, out);
    }
}

// Round 6
// 240.386 us; speedup vs baseline: 2.2395x; 1.0019x over previous
//
#include <hip/hip_runtime.h>
#include <hip/hip_bf16.h>
#include <math.h>

#define BATCH 2
#define NQ    13125
#define MQ    26250   // BATCH*NQ
#define DM    256
#define NH    8
#define HDIM  32
#define NL    3
#define NP    4
#define NTOK  13125   // value tokens per batch (10000+2500+625)

typedef __attribute__((ext_vector_type(8))) short bf16x8;
typedef __attribute__((ext_vector_type(8))) unsigned short u16x8;
typedef __attribute__((ext_vector_type(4))) float f32x4;

__device__ __forceinline__ short f2bf(float f) {
    unsigned u = __float_as_uint(f);
    unsigned r = (u + 0x7FFFu + ((u >> 16) & 1u)) >> 16;
    return (short)r;
}
__device__ __forceinline__ float bf2f(unsigned short u) {
    return __uint_as_float((unsigned)u << 16);
}

// async global->LDS, 16B per lane. LDS dest must be wave-uniform base + lane*16.
__device__ __forceinline__ void gld_lds16(const short* g, short* l) {
    __builtin_amdgcn_global_load_lds(
        (const __attribute__((address_space(1))) unsigned int*)g,
        (__attribute__((address_space(3))) unsigned int*)l, 16, 0, 0);
}

// ---------------- weight prep: Wt[n][k] bf16 <- W[k][n] fp32 (K=256), + zero pad ----------------
// layout: Wt_val rows 0..255 | Wt_off rows: Wo 0..191, Wa 192..287, pad 288..383 | Wt_out 256 rows
__global__ __launch_bounds__(256) void wprep_kernel(const float* __restrict__ Wv,
                                                    const float* __restrict__ Wo,
                                                    const float* __restrict__ Wa,
                                                    const float* __restrict__ Wu,
                                                    short* __restrict__ Wt)
{
    const int w = blockIdx.y;
    const int Ns[5]   = {256, 192, 96, 256, 96};
    const int Offs[5] = {0, 65536, 114688, 163840, 139264};
    const int N = Ns[w];
    const int flat = blockIdx.x * 256 + threadIdx.x;
    const int n = flat >> 8, k = flat & 255;
    if (n >= N) return;
    if (w == 4) { Wt[139264 + n * 256 + k] = 0; return; }
    const float* W = (w == 0) ? Wv : ((w == 1) ? Wo : ((w == 2) ? Wa : Wu));
    Wt[Offs[w] + n * 256 + k] = f2bf(W[k * N + n]);
}

// ---------------- activation convert fp32 -> bf16; values go into concatenated vcat layout ------
__global__ __launch_bounds__(256) void cvt_kernel(const float* __restrict__ q,
                                                  const float* __restrict__ v0,
                                                  const float* __restrict__ v1,
                                                  const float* __restrict__ v2,
                                                  short* __restrict__ qb,
                                                  short* __restrict__ vcat)
{
    const int t = blockIdx.y;
    const int sz4[4] = {MQ * 64, 2 * 10000 * 64, 2 * 2500 * 64, 2 * 625 * 64};
    const int i = blockIdx.x * 256 + threadIdx.x;
    if (i >= sz4[t]) return;
    const int row = i >> 6, c = i & 63;
    const float* src = (t == 0) ? q : ((t == 1) ? v0 : ((t == 2) ? v1 : v2));
    int orow;
    short* dst;
    if (t == 0)      { orow = row;                                        dst = qb; }
    else if (t == 1) { orow = (row / 10000) * NTOK + (row % 10000);       dst = vcat; }
    else if (t == 2) { orow = (row / 2500) * NTOK + 10000 + (row % 2500); dst = vcat; }
    else             { orow = (row / 625) * NTOK + 12500 + (row % 625);   dst = vcat; }
    float4 v = ((const float4*)src)[i];
    short4 o;
    o.x = f2bf(v.x); o.y = f2bf(v.y); o.z = f2bf(v.z); o.w = f2bf(v.w);
    ((short4*)dst)[orow * 64 + c] = o;
}

// ---------------- 128x128-tile bf16 MFMA GEMM, M=MQ, K=256 ----------------
// A bf16 [M][256], Wt bf16 [NN][256]. EPI: 0 fp32 C, 1 bf16 C, 2 split offs/lgts.
// LDS: [128][32] bf16, NO padding (global_load_lds); k-granule XOR swizzle p = kq ^ ((row>>1)&3).
template<int EPI, int NN>
__global__ __launch_bounds__(256) void gemm128(const short* __restrict__ A,
                                               const short* __restrict__ Wt,
                                               const float* __restrict__ bias0,
                                               const float* __restrict__ bias1,
                                               void* __restrict__ C0,
                                               void* __restrict__ C1)
{
    __shared__ short As[128 * 32];
    __shared__ short Bs[128 * 32];

    const int tid  = threadIdx.x;
    const int m0   = blockIdx.y * 128;
    const int n0   = blockIdx.x * 128;
    const int lane = tid & 63;
    const int wave = tid >> 6;
    const int wm   = (wave & 1) * 64;
    const int wn   = (wave >> 1) * 64;
    const int ml   = lane & 15;
    const int kq   = lane >> 4;

    // staging: granule g = j*256+tid; row=g>>2; pcol=g&3; fetch global kq = pcol ^ ((row>>1)&3)
    const int row0 = tid >> 2;
    const int row1 = row0 + 64;
    const int kqs  = (tid & 3) ^ ((row0 >> 1) & 3);   // same swizzle class for row1
    const short* gA0 = A  + (size_t)(m0 + row0) * 256 + kqs * 8;
    const short* gA1 = A  + (size_t)(m0 + row1) * 256 + kqs * 8;
    const short* gB0 = Wt + (size_t)(n0 + row0) * 256 + kqs * 8;
    const short* gB1 = Wt + (size_t)(n0 + row1) * 256 + kqs * 8;
    short* lA0 = As + tid * 8;
    short* lA1 = As + (256 + tid) * 8;
    short* lB0 = Bs + tid * 8;
    short* lB1 = Bs + (256 + tid) * 8;
    const bool a0ok = (m0 + row0) < MQ;
    const bool a1ok = (m0 + row1) < MQ;

    f32x4 acc[4][4] = {};

    for (int k0 = 0; k0 < 256; k0 += 32) {
        if (a0ok) gld_lds16(gA0 + k0, lA0);
        if (a1ok) gld_lds16(gA1 + k0, lA1);
        gld_lds16(gB0 + k0, lB0);
        gld_lds16(gB1 + k0, lB1);
        __syncthreads();

        bf16x8 af[4], bfr[4];
#pragma unroll
        for (int ti = 0; ti < 4; ++ti) {
            const int r = wm + ti * 16 + ml;
            af[ti] = *(const bf16x8*)&As[r * 32 + ((kq ^ ((r >> 1) & 3)) << 3)];
        }
#pragma unroll
        for (int tj = 0; tj < 4; ++tj) {
            const int r = wn + tj * 16 + ml;
            bfr[tj] = *(const bf16x8*)&Bs[r * 32 + ((kq ^ ((r >> 1) & 3)) << 3)];
        }
#pragma unroll
        for (int ti = 0; ti < 4; ++ti)
#pragma unroll
            for (int tj = 0; tj < 4; ++tj)
                acc[ti][tj] = __builtin_amdgcn_mfma_f32_16x16x32_bf16(af[ti], bfr[tj], acc[ti][tj], 0, 0, 0);

        __syncthreads();
    }

    // C/D layout: col = lane&15, row = (lane>>4)*4 + reg
#pragma unroll
    for (int tj = 0; tj < 4; ++tj) {
        const int gn = n0 + wn + tj * 16 + ml;
#pragma unroll
        for (int ti = 0; ti < 4; ++ti) {
#pragma unroll
            for (int r = 0; r < 4; ++r) {
                const int gm = m0 + wm + ti * 16 + kq * 4 + r;
                if (gm >= MQ) continue;
                const float v = acc[ti][tj][r];
                if (EPI == 0) {
                    ((float*)C0)[(size_t)gm * NN + gn] = v + bias0[gn];
                } else if (EPI == 1) {
                    ((short*)C0)[(size_t)gm * NN + gn] = f2bf(v + bias0[gn]);
                } else {
                    if (gn < 192)      ((float*)C0)[(size_t)gm * 192 + gn]        = v + bias0[gn];
                    else if (gn < 288) ((float*)C1)[(size_t)gm * 96 + (gn - 192)] = v + bias1[gn - 192];
                }
            }
        }
    }
}

// ---------------- sampling: 4 queries/block, 32 lanes/query, 16B bf16 gathers ----------------
__global__ __launch_bounds__(128) void sample_kernel(const short* __restrict__ vws,
                                                     const float* __restrict__ offs,
                                                     const float* __restrict__ logits,
                                                     const float* __restrict__ refp,
                                                     short* __restrict__ mid)
{
    const int q0  = blockIdx.x * 4;
    const int tid = threadIdx.x;

    __shared__ float  s_lg[4][96];
    __shared__ float  s_ref[4][6];
    __shared__ float  s_stat[4][NH][2];
    __shared__ float4 s_w[4][96];
    __shared__ int4   s_i[4][96];   // byte offsets (row*512)

    // Phase A: stage logits + refs
    for (int idx = tid; idx < 384; idx += 128) {
        const int qq = idx / 96, s = idx % 96;
        if (q0 + qq < MQ) s_lg[qq][s] = logits[(size_t)(q0 + qq) * 96 + s];
    }
    if (tid < 24) {
        const int qq = tid / 6, j = tid % 6;
        if (q0 + qq < MQ) s_ref[qq][j] = refp[(size_t)(q0 + qq) * 6 + j];
    }
    __syncthreads();

    // Phase B: per-head softmax stats
    if (tid < 32) {
        const int qq = tid >> 3, h = tid & 7;
        if (q0 + qq < MQ) {
            float mx = -1e30f;
#pragma unroll
            for (int i = 0; i < 12; ++i) mx = fmaxf(mx, s_lg[qq][h * 12 + i]);
            float ssum = 0.f;
#pragma unroll
            for (int i = 0; i < 12; ++i) ssum += expf(s_lg[qq][h * 12 + i] - mx);
            s_stat[qq][h][0] = mx;
            s_stat[qq][h][1] = 1.f / ssum;
        }
    }
    __syncthreads();

    // Phase C: folded corner weights + byte-offset indices
    for (int idx = tid; idx < 384; idx += 128) {
        const int qq = idx / 96, s = idx % 96;
        const int q  = q0 + qq;
        if (q >= MQ) continue;
        const int b  = q / NQ;
        const int h  = s / 12, i = s % 12;
        const int l  = i >> 2, p = i & 3;

        const int Hs[3] = {100, 50, 25};
        const int Wz[3] = {100, 50, 25};
        const int Lo[3] = {0, 10000, 12500};
        const int Wl = Wz[l], Hl = Hs[l];
        const float fW = (float)Wl, fH = (float)Hl;

        const float aw = expf(s_lg[qq][s] - s_stat[qq][h][0]) * s_stat[qq][h][1];

        const int oi = (((h * NL) + l) * NP + p) * 2;
        const float2 offp = *(const float2*)(offs + (size_t)q * 192 + oi);
        const float rx = s_ref[qq][l * 2 + 0];
        const float ry = s_ref[qq][l * 2 + 1];

        const float x = (rx + offp.x / fW) * fW - 0.5f;
        const float y = (ry + offp.y / fH) * fH - 0.5f;
        const float x0f = floorf(x), y0f = floorf(y);
        const int   x0 = (int)x0f,  y0 = (int)y0f;
        const float wx1 = x - x0f, wy1 = y - y0f;
        const float wx0 = 1.f - wx1, wy0 = 1.f - wy1;

        const bool xin0 = (x0 >= 0) && (x0 < Wl);
        const bool xin1 = (x0 + 1 >= 0) && (x0 + 1 < Wl);
        const bool yin0 = (y0 >= 0) && (y0 < Hl);
        const bool yin1 = (y0 + 1 >= 0) && (y0 + 1 < Hl);

        const int cx0 = min(max(x0, 0), Wl - 1);
        const int cx1 = min(max(x0 + 1, 0), Wl - 1);
        const int cy0 = min(max(y0, 0), Hl - 1);
        const int cy1 = min(max(y0 + 1, 0), Hl - 1);

        const int base = b * NTOK + Lo[l];
        int4 idxv;
        idxv.x = (base + cy0 * Wl + cx0) * 512;
        idxv.y = (base + cy0 * Wl + cx1) * 512;
        idxv.z = (base + cy1 * Wl + cx0) * 512;
        idxv.w = (base + cy1 * Wl + cx1) * 512;

        float4 w;
        w.x = (xin0 && yin0) ? aw * wx0 * wy0 : 0.f;
        w.y = (xin1 && yin0) ? aw * wx1 * wy0 : 0.f;
        w.z = (xin0 && yin1) ? aw * wx0 * wy1 : 0.f;
        w.w = (xin1 && yin1) ? aw * wx1 * wy1 : 0.f;

        s_w[qq][s] = w;
        s_i[qq][s] = idxv;
    }
    __syncthreads();

    // Phase D: gather-FMA, 32 lanes/query, 8 bf16 channels per lane (16B loads)
    {
        const int qq = tid >> 5;
        const int q  = q0 + qq;
        if (q < MQ) {
            const int r  = tid & 31;
            const int h  = r >> 2;
            const int c8 = (r & 3) * 8;
            const int ch = h * HDIM + c8;
            const char* vb = (const char*)vws + (size_t)ch * 2;

            float a[8] = {};
#pragma unroll
            for (int s = 0; s < 12; ++s) {
                const float4 w  = s_w[qq][h * 12 + s];
                const int4   id = s_i[qq][h * 12 + s];
                const u16x8 u0 = *(const u16x8*)(vb + id.x);
                const u16x8 u1 = *(const u16x8*)(vb + id.y);
                const u16x8 u2 = *(const u16x8*)(vb + id.z);
                const u16x8 u3 = *(const u16x8*)(vb + id.w);
#pragma unroll
                for (int j = 0; j < 8; ++j)
                    a[j] += w.x * bf2f(u0[j]) + w.y * bf2f(u1[j]) + w.z * bf2f(u2[j]) + w.w * bf2f(u3[j]);
            }
            union { u16x8 v; unsigned short s[8]; } o;
#pragma unroll
            for (int j = 0; j < 8; ++j) o.s[j] = (unsigned short)f2bf(a[j]);
            *(u16x8*)(mid + (size_t)q * DM + ch) = o.v;
        }
    }
}

// ---------------------------------------------------------------------------------------------
extern "C" void kernel_launch(void* const* d_in, const int* in_sizes, int n_in,
                              void* d_out, int out_size, void* d_ws, size_t ws_size,
                              hipStream_t stream)
{
    const float* query  = (const float*)d_in[0];
    const float* refp   = (const float*)d_in[1];
    const float* v0     = (const float*)d_in[2];
    const float* v1     = (const float*)d_in[3];
    const float* v2     = (const float*)d_in[4];
    const float* W_val  = (const float*)d_in[5];
    const float* b_val  = (const float*)d_in[6];
    const float* W_off  = (const float*)d_in[7];
    const float* b_off  = (const float*)d_in[8];
    const float* W_attn = (const float*)d_in[9];
    const float* b_attn = (const float*)d_in[10];
    const float* W_out  = (const float*)d_in[11];
    const float* b_out  = (const float*)d_in[12];
    float* out = (float*)d_out;

    float* ws   = (float*)d_ws;
    float* offs = ws;                                    // MQ*192 f32
    float* lgts = offs + (size_t)MQ * 192;               // MQ*96 f32
    short* vws  = (short*)(lgts + (size_t)MQ * 96);      // MQ*256 bf16 (projected values)
    short* mid  = vws + (size_t)MQ * DM;                 // MQ*256 bf16
    short* qbf  = mid + (size_t)MQ * DM;                 // MQ*256 bf16
    short* vcat = qbf + (size_t)MQ * DM;                 // MQ*256 bf16 (raw values, concat layout)
    short* Wt   = vcat + (size_t)MQ * DM;                // 229376 bf16
    short* Wt_val = Wt;                                  // rows 0..255
    short* Wt_off = Wt + 65536;                          // 384 rows: off|attn|pad
    short* Wt_out = Wt + 163840;                         // 256 rows

    // 0a. weights -> bf16 transposed (+ zero pad rows 288..383 of fused block)
    {
        dim3 grid(256, 5);
        wprep_kernel<<<grid, 256, 0, stream>>>(W_val, W_off, W_attn, W_out, Wt);
    }
    // 0b. activations -> bf16 (query + concatenated values)
    {
        dim3 grid((MQ * 64 + 255) / 256, 4);
        cvt_kernel<<<grid, 256, 0, stream>>>(query, v0, v1, v2, qbf, vcat);
    }
    // 1. value projection -> vws (bf16)
    {
        dim3 grid(2, (MQ + 127) / 128);
        gemm128<1, 256><<<grid, 256, 0, stream>>>(vcat, Wt_val, b_val, nullptr, vws, nullptr);
    }
    // 2. fused offsets+logits (N padded to 384)
    {
        dim3 grid(3, (MQ + 127) / 128);
        gemm128<2, 384><<<grid, 256, 0, stream>>>(qbf, Wt_off, b_off, b_attn, offs, lgts);
    }
    // 3. softmax + bilinear sampling -> mid (bf16)
    sample_kernel<<<(MQ + 3) / 4, 128, 0, stream>>>(vws, offs, lgts, refp, mid);
    // 4. output projection -> out (fp32)
    {
        dim3 grid(2, (MQ + 127) / 128);
        gemm128<0, 256><<<grid, 256, 0, stream>>>(mid, Wt_out, b_out, nullptr, out, nullptr);
    }
}